// Round 5
// baseline (30241.528 us; speedup 1.0000x reference)
//
#include <hip/hip_runtime.h>
#include <hip/hip_bf16.h>

// xLSTMStack: proj -> 4x( LN -> conv-mix -> bf16 MFMA GEMM (xg) -> cooperative GRU scan + residual )
// GRU v5: batched-MFMA formulation. 8 WGs x 384 threads; WG owns 64 h-dims
// (192 gate-rows = r,z,n triples). Step = h[16x512] @ Whh^T via 16x16x32 MFMA,
// weights live as bf16 MFMA B-fragments in VGPRs (2 tiles x 16 k-slices/wave).
// Cross-WG h-exchange: tagged u64 {tag32, 2xbf16}, 4096 slots, parallel polls.
// Workspace (~134.1 MiB):
//   [0,96M)    xg bf16 [B*L*3H] (first 64 MiB aliased as ln fp32)
//   [96,128M)  mixbf bf16 [B*L*H]
//   [128,134M) wihbf bf16 [4*3H*H]
//   [134M,+64K) hst u64 [2][16][256]
// d_out (fp32 [B,L,H]) doubles as the inter-layer h buffer.

#define B_   16
#define L_   2048
#define IN_  64
#define H_   512
#define H3_  1536
#define NL_  4

typedef unsigned short u16;
typedef unsigned long long u64;
typedef short bf16x8 __attribute__((ext_vector_type(8)));
typedef float f32x4 __attribute__((ext_vector_type(4)));
typedef u16 u16x4 __attribute__((ext_vector_type(4)));

__device__ __forceinline__ u16 f2bf(float f) {
  unsigned u = __float_as_uint(f);
  u = u + 0x7fffu + ((u >> 16) & 1u);
  return (u16)(u >> 16);
}
__device__ __forceinline__ float bf2f(u16 v) {
  return __uint_as_float(((unsigned)v) << 16);
}
__device__ __forceinline__ float gelu_exact(float x) {
  return 0.5f * x * (1.f + erff(x * 0.70710678118654752440f));
}
__device__ __forceinline__ float fast_sig(float x) {
  float e = __expf(-x);
  return __builtin_amdgcn_rcpf(1.f + e);
}
__device__ __forceinline__ float fast_tanh(float x) {
  x = fminf(fmaxf(x, -15.f), 15.f);
  float e = __expf(2.f * x);
  return (e - 1.f) * __builtin_amdgcn_rcpf(e + 1.f);
}

// ---------------- init: zero tagged h-state ----------------
__global__ void k_init(u64* hst, int n) {
  int i = blockIdx.x * blockDim.x + threadIdx.x;
  if (i < n) hst[i] = 0ull;
}

// ---------------- fp32 -> bf16 convert ----------------
__global__ void k_cvt(const float* __restrict__ in, u16* __restrict__ out, int n) {
  int i = blockIdx.x * blockDim.x + threadIdx.x;
  int stride = gridDim.x * blockDim.x;
  for (; i < n; i += stride) out[i] = f2bf(in[i]);
}

// ---------------- input projection: h = x @ Wp.T + bp ----------------
__global__ __launch_bounds__(512)
void k_proj(const float* __restrict__ x, const float* __restrict__ Wp,
            const float* __restrict__ bp, float* __restrict__ hb) {
  __shared__ float4 xs[128];
  const int tid = threadIdx.x;
  const size_t m0 = (size_t)blockIdx.x * 8;
  if (tid < 128) xs[tid] = ((const float4*)(x + m0 * IN_))[tid];
  __syncthreads();
  float4 wv[16];
  const float4* wp4 = (const float4*)(Wp + (size_t)tid * IN_);
#pragma unroll
  for (int i = 0; i < 16; ++i) wv[i] = wp4[i];
  float acc[8] = {0.f,0.f,0.f,0.f,0.f,0.f,0.f,0.f};
#pragma unroll
  for (int k = 0; k < 16; ++k) {
    float4 w4 = wv[k];
#pragma unroll
    for (int rr = 0; rr < 8; ++rr) {
      float4 xv = xs[rr * 16 + k];
      acc[rr] += w4.x * xv.x + w4.y * xv.y + w4.z * xv.z + w4.w * xv.w;
    }
  }
  float bpv = bp[tid];
#pragma unroll
  for (int rr = 0; rr < 8; ++rr) hb[(m0 + rr) * H_ + tid] = acc[rr] + bpv;
}

// ---------------- LayerNorm (one wave per row) ----------------
__global__ __launch_bounds__(256)
void k_ln(const float* __restrict__ hin, const float* __restrict__ g,
          const float* __restrict__ bta, float* __restrict__ lnout) {
  const int w = threadIdx.x >> 6, lane = threadIdx.x & 63;
  const size_t m = (size_t)blockIdx.x * 4 + w;
  const float4* src = (const float4*)(hin + m * H_);
  float4 a = src[lane * 2], c = src[lane * 2 + 1];
  float sm = a.x + a.y + a.z + a.w + c.x + c.y + c.z + c.w;
  float sq = a.x*a.x + a.y*a.y + a.z*a.z + a.w*a.w + c.x*c.x + c.y*c.y + c.z*c.z + c.w*c.w;
  sm += __shfl_xor(sm, 1);  sq += __shfl_xor(sq, 1);
  sm += __shfl_xor(sm, 2);  sq += __shfl_xor(sq, 2);
  sm += __shfl_xor(sm, 4);  sq += __shfl_xor(sq, 4);
  sm += __shfl_xor(sm, 8);  sq += __shfl_xor(sq, 8);
  sm += __shfl_xor(sm, 16); sq += __shfl_xor(sq, 16);
  sm += __shfl_xor(sm, 32); sq += __shfl_xor(sq, 32);
  float mu = sm * (1.f / 512.f);
  float var = sq * (1.f / 512.f) - mu * mu;
  float inv = 1.f / sqrtf(var + 1e-5f);
  const float4* g4 = (const float4*)g;
  const float4* b4 = (const float4*)bta;
  float4 ga = g4[lane * 2], gc = g4[lane * 2 + 1];
  float4 ba = b4[lane * 2], bc = b4[lane * 2 + 1];
  float4 oa, oc;
  oa.x = (a.x - mu) * inv * ga.x + ba.x;
  oa.y = (a.y - mu) * inv * ga.y + ba.y;
  oa.z = (a.z - mu) * inv * ga.z + ba.z;
  oa.w = (a.w - mu) * inv * ga.w + ba.w;
  oc.x = (c.x - mu) * inv * gc.x + bc.x;
  oc.y = (c.y - mu) * inv * gc.y + bc.y;
  oc.z = (c.z - mu) * inv * gc.z + bc.z;
  oc.w = (c.w - mu) * inv * gc.w + bc.w;
  float4* dst = (float4*)(lnout + m * H_);
  dst[lane * 2] = oa;
  dst[lane * 2 + 1] = oc;
}

// ---------------- fused conv(5,11,23)+BN+GELU+gate softmax+mix ----------------
__global__ __launch_bounds__(512)
void k_mix(const float* __restrict__ ln,
           const float* __restrict__ w0, const float* __restrict__ cb0,
           const float* __restrict__ w1, const float* __restrict__ cb1,
           const float* __restrict__ w2, const float* __restrict__ cb2,
           const float* __restrict__ bng, const float* __restrict__ bnb,
           const float* __restrict__ gW, const float* __restrict__ gb,
           u16* __restrict__ mixbf) {
  const int h = threadIdx.x;
  const int bi = blockIdx.x >> 11;
  const int t = blockIdx.x & (L_ - 1);
  const size_t mrow = (size_t)blockIdx.x;
  float v[23];
#pragma unroll
  for (int d = 0; d < 23; ++d) {
    int tt = t + d - 11;
    v[d] = (tt >= 0 && tt < L_) ? ln[((size_t)bi * L_ + tt) * H_ + h] : 0.f;
  }
  float o0 = cb0[h], o1 = cb1[h], o2 = cb2[h];
#pragma unroll
  for (int d = 0; d < 5; ++d) o0 += v[9 + d] * w0[h * 5 + d];
#pragma unroll
  for (int d = 0; d < 11; ++d) o1 += v[6 + d] * w1[h * 11 + d];
#pragma unroll
  for (int d = 0; d < 23; ++d) o2 += v[d] * w2[h * 23 + d];
  const float bscale = 0.99999500003749968f;  // 1/sqrt(1+1e-5)
  o0 = o0 * (bng[0 * H_ + h] * bscale) + bnb[0 * H_ + h];
  o1 = o1 * (bng[1 * H_ + h] * bscale) + bnb[1 * H_ + h];
  o2 = o2 * (bng[2 * H_ + h] * bscale) + bnb[2 * H_ + h];
  o0 = gelu_exact(o0); o1 = gelu_exact(o1); o2 = gelu_exact(o2);
  float l0 = o0 * gW[0 * H3_ + h] + o1 * gW[0 * H3_ + H_ + h] + o2 * gW[0 * H3_ + 2 * H_ + h];
  float l1 = o0 * gW[1 * H3_ + h] + o1 * gW[1 * H3_ + H_ + h] + o2 * gW[1 * H3_ + 2 * H_ + h];
  float l2 = o0 * gW[2 * H3_ + h] + o1 * gW[2 * H3_ + H_ + h] + o2 * gW[2 * H3_ + 2 * H_ + h];
  l0 += __shfl_xor(l0, 1);  l1 += __shfl_xor(l1, 1);  l2 += __shfl_xor(l2, 1);
  l0 += __shfl_xor(l0, 2);  l1 += __shfl_xor(l1, 2);  l2 += __shfl_xor(l2, 2);
  l0 += __shfl_xor(l0, 4);  l1 += __shfl_xor(l1, 4);  l2 += __shfl_xor(l2, 4);
  l0 += __shfl_xor(l0, 8);  l1 += __shfl_xor(l1, 8);  l2 += __shfl_xor(l2, 8);
  l0 += __shfl_xor(l0, 16); l1 += __shfl_xor(l1, 16); l2 += __shfl_xor(l2, 16);
  l0 += __shfl_xor(l0, 32); l1 += __shfl_xor(l1, 32); l2 += __shfl_xor(l2, 32);
  __shared__ float red[8][3];
  const int w = h >> 6, lane = h & 63;
  if (lane == 0) { red[w][0] = l0; red[w][1] = l1; red[w][2] = l2; }
  __syncthreads();
  l0 = gb[0]; l1 = gb[1]; l2 = gb[2];
#pragma unroll
  for (int i = 0; i < 8; ++i) { l0 += red[i][0]; l1 += red[i][1]; l2 += red[i][2]; }
  float mx = fmaxf(l0, fmaxf(l1, l2));
  float e0 = expf(l0 - mx), e1 = expf(l1 - mx), e2 = expf(l2 - mx);
  float inv = 1.f / (e0 + e1 + e2);
  float out = (o0 * e0 + o1 * e1 + o2 * e2) * inv;
  mixbf[mrow * H_ + h] = f2bf(out);
}

// ---------------- bf16 MFMA GEMM: xg = mixbf @ WihT + bih ----------------
__global__ __launch_bounds__(256)
void k_gemm(const u16* __restrict__ A, const u16* __restrict__ Bm,
            const float* __restrict__ bias, u16* __restrict__ C) {
  __shared__ u16 As[128 * 32];
  __shared__ u16 Bs[128 * 32];
  const int tid = threadIdx.x;
  const int bm = blockIdx.x / 12, bn = blockIdx.x % 12;
  const int m0 = bm * 128, n0 = bn * 128;
  const int w = tid >> 6, lane = tid & 63;
  const int wr = w >> 1, wc = w & 1;
  const int q = lane >> 4, r = lane & 15;
  f32x4 acc[4][4] = {};
  const uint4* Ag = (const uint4*)(A + (size_t)m0 * H_);
  const uint4* Bg = (const uint4*)(Bm + (size_t)n0 * H_);
  uint4* As4 = (uint4*)As;
  uint4* Bs4 = (uint4*)Bs;
  for (int ko = 0; ko < 16; ++ko) {
    __syncthreads();
#pragma unroll
    for (int i = 0; i < 2; ++i) {
      int j = tid + 256 * i;
      As4[j] = Ag[(size_t)(j >> 2) * 64 + (j & 3) + ko * 4];
      Bs4[j] = Bg[(size_t)(j >> 2) * 64 + (j & 3) + ko * 4];
    }
    __syncthreads();
    bf16x8 av[4], bv[4];
#pragma unroll
    for (int m = 0; m < 4; ++m) av[m] = *(const bf16x8*)&As[(wr * 64 + m * 16 + r) * 32 + q * 8];
#pragma unroll
    for (int n = 0; n < 4; ++n) bv[n] = *(const bf16x8*)&Bs[(wc * 64 + n * 16 + r) * 32 + q * 8];
#pragma unroll
    for (int m = 0; m < 4; ++m)
#pragma unroll
      for (int n = 0; n < 4; ++n)
        acc[m][n] = __builtin_amdgcn_mfma_f32_16x16x32_bf16(av[m], bv[n], acc[m][n], 0, 0, 0);
  }
#pragma unroll
  for (int n = 0; n < 4; ++n) {
    int col = n0 + wc * 64 + n * 16 + r;
    float bv_ = bias[col];
#pragma unroll
    for (int m = 0; m < 4; ++m) {
      int row = m0 + wr * 64 + m * 16 + q * 4;
#pragma unroll
      for (int i = 0; i < 4; ++i) {
        float v = acc[m][n][i] + bv_;
        C[(size_t)(row + i) * H3_ + col] = f2bf(v);
      }
    }
  }
}

// ---------------- cooperative GRU scan, batched MFMA ----------------
// 8 WGs x 384 threads (6 waves). WG owns dims [64wg, 64wg+64) = 192 gate-rows.
// Wave v: tiles tau=2v,2v+1; tile tau: gate g=tau>>2, dims [(tau&3)*16,+16).
// Per step: MFMA h[16x512]@W^T -> pre[3][16][64] in LDS -> gate threads
// (tid<256: b=tid>>4, 4 dims each) compute gates fp32, publish {tag,2bf16} u64.
// h in LDS: bf16 [16][512], 16B-slot XOR-swizzle (slot ^= b&7).
__global__ __launch_bounds__(384, 1)
void k_gru(const float* __restrict__ Whh_l, const float* __restrict__ bhh_l,
           const u16* __restrict__ xg, const u16* __restrict__ mixbf,
           float* __restrict__ out_h, u64* hst, int tbase) {
  const int tid = threadIdx.x;
  const int wg = blockIdx.x;          // 0..7
  const int wv = tid >> 6;            // wave 0..5
  const int lane = tid & 63;
  const int q = lane >> 4, r = lane & 15;
  const int J0 = wg * 64;

  __shared__ __align__(16) u16 h_lds[2][16][512];   // 32 KB, swizzled bf16
  __shared__ __align__(16) float pre[3][16][72];    // ~13.8 KB

  // --- weight fragments: fp32 global -> bf16 VGPR, 2 tiles x 16 k-slices ---
  bf16x8 wf0[16], wf1[16];
  {
    const int tau0 = wv * 2;
    const int g0 = tau0 >> 2, jt0 = tau0 & 3;
    const int tau1 = tau0 + 1;
    const int g1 = tau1 >> 2, jt1 = tau1 & 3;
    const float* s0 = Whh_l + (size_t)((g0 << 9) + J0 + jt0 * 16 + r) * H_ + q * 8;
    const float* s1 = Whh_l + (size_t)((g1 << 9) + J0 + jt1 * 16 + r) * H_ + q * 8;
#pragma unroll
    for (int kk = 0; kk < 16; ++kk) {
      bf16x8 f0, f1;
#pragma unroll
      for (int e = 0; e < 8; ++e) {
        f0[e] = (short)f2bf(s0[kk * 32 + e]);
        f1[e] = (short)f2bf(s1[kk * 32 + e]);
      }
      wf0[kk] = f0; wf1[kk] = f1;
    }
  }

  // gate-thread statics
  const bool gate = (tid < 256);
  const int gb = (tid >> 4) & 15;             // batch
  const int j4 = (tid & 15) << 2;             // local dim base (0..60)
  const int gd0 = J0 + j4;                    // global dim base
  f32x4 br4 = {}, bz4 = {}, bn4 = {};
  if (gate) {
    br4 = *(const f32x4*)(bhh_l + 0 * H_ + gd0);
    bz4 = *(const f32x4*)(bhh_l + 1 * H_ + gd0);
    bn4 = *(const f32x4*)(bhh_l + 2 * H_ + gd0);
  }
  const u16* xgp = xg + (size_t)gb * L_ * H3_ + gd0;
  const u16* mxp = mixbf + (size_t)gb * L_ * H_ + gd0;
  float* outp = out_h + (size_t)gb * L_ * H_ + gd0;
  f32x4 hp = {};

  // zero h parity 0
  for (int i = tid; i < 4096; i += 384) ((unsigned*)&h_lds[0][0][0])[i] = 0u;
  __syncthreads();

  // prefetch xg/mix for t=0
  u16x4 xr_c = {}, xz_c = {}, xn_c = {}, mx_c = {};
  if (gate) {
    xr_c = *(const u16x4*)(xgp + 0 * H_);
    xz_c = *(const u16x4*)(xgp + 1 * H_);
    xn_c = *(const u16x4*)(xgp + 2 * H_);
    mx_c = *(const u16x4*)(mxp);
  }

  for (int t = 0; t < L_; ++t) {
    const int par = t & 1, p1 = (t + 1) & 1;
    const unsigned T = (unsigned)(tbase + t + 1);
    u64* hsp = hst + (size_t)p1 * 4096;

    // prefetch next step's gate inputs (hide HBM latency under MFMA+sync)
    u16x4 xr_n = {}, xz_n = {}, xn_n = {}, mx_n = {};
    if (gate && t + 1 < L_) {
      const u16* xq = xgp + (size_t)(t + 1) * H3_;
      xr_n = *(const u16x4*)(xq + 0 * H_);
      xz_n = *(const u16x4*)(xq + 1 * H_);
      xn_n = *(const u16x4*)(xq + 2 * H_);
      mx_n = *(const u16x4*)(mxp + (size_t)(t + 1) * H_);
    }

    // ---- MFMA phase: pre = h @ W^T for 2 tiles ----
    f32x4 acc0 = {}, acc1 = {};
    {
      const u16* hb = &h_lds[par][r][0];
#pragma unroll
      for (int kk = 0; kk < 16; ++kk) {
        int sl = (kk * 4 + q) ^ (r & 7);
        bf16x8 a = *(const bf16x8*)(hb + sl * 8);
        acc0 = __builtin_amdgcn_mfma_f32_16x16x32_bf16(a, wf0[kk], acc0, 0, 0, 0);
        acc1 = __builtin_amdgcn_mfma_f32_16x16x32_bf16(a, wf1[kk], acc1, 0, 0, 0);
      }
    }
    {
      const int tau0 = wv * 2, g0 = tau0 >> 2, jt0 = tau0 & 3;
      const int tau1 = tau0 + 1, g1 = tau1 >> 2, jt1 = tau1 & 3;
#pragma unroll
      for (int i = 0; i < 4; ++i) {
        pre[g0][q * 4 + i][jt0 * 16 + r] = acc0[i];
        pre[g1][q * 4 + i][jt1 * 16 + r] = acc1[i];
      }
    }
    __syncthreads();

    // ---- gate phase + publish ----
    if (gate) {
      f32x4 pr = *(const f32x4*)&pre[0][gb][j4];
      f32x4 pz = *(const f32x4*)&pre[1][gb][j4];
      f32x4 pn = *(const f32x4*)&pre[2][gb][j4];
      f32x4 hn;
#pragma unroll
      for (int i = 0; i < 4; ++i) {
        float rr = fast_sig(bf2f(xr_c[i]) + pr[i] + br4[i]);
        float zz = fast_sig(bf2f(xz_c[i]) + pz[i] + bz4[i]);
        float nn = fast_tanh(bf2f(xn_c[i]) + rr * (pn[i] + bn4[i]));
        hn[i] = nn + zz * (hp[i] - nn);
      }
      hp = hn;
      u16 b0 = f2bf(hn[0]), b1 = f2bf(hn[1]), b2 = f2bf(hn[2]), b3 = f2bf(hn[3]);
      if (t + 1 < L_) {
        unsigned lo01 = (unsigned)b0 | ((unsigned)b1 << 16);
        unsigned lo23 = (unsigned)b2 | ((unsigned)b3 << 16);
        int P0 = gd0 >> 1;
        __hip_atomic_store(&hsp[(gb << 8) + P0], ((u64)T << 32) | lo01,
                           __ATOMIC_RELAXED, __HIP_MEMORY_SCOPE_AGENT);
        __hip_atomic_store(&hsp[(gb << 8) + P0 + 1], ((u64)T << 32) | lo23,
                           __ATOMIC_RELAXED, __HIP_MEMORY_SCOPE_AGENT);
        // own slice straight to (swizzled) LDS
        int sl = (gd0 >> 3) ^ (gb & 7);
        u16x4 pk = { b0, b1, b2, b3 };
        *(u16x4*)(&h_lds[p1][gb][sl * 8 + (gd0 & 7)]) = pk;
      }
      // residual output
      f32x4 ov;
#pragma unroll
      for (int i = 0; i < 4; ++i) ov[i] = bf2f(mx_c[i]) + hn[i];
      *(f32x4*)(outp + (size_t)t * H_) = ov;
    }

    // ---- poll remote slices into h_lds[p1] ----
    if (t + 1 < L_) {
      unsigned donemask = 0;
      bool alldone;
      do {
        u64 v[11];
#pragma unroll
        for (int i = 0; i < 11; ++i) {
          int sg = tid + 384 * i;
          bool act = (sg < 4096) && (((sg >> 5) & 7) != wg) && !(donemask & (1u << i));
          v[i] = act ? __hip_atomic_load(&hsp[sg], __ATOMIC_RELAXED, __HIP_MEMORY_SCOPE_AGENT) : 0ull;
        }
        alldone = true;
#pragma unroll
        for (int i = 0; i < 11; ++i) {
          int sg = tid + 384 * i;
          bool act = (sg < 4096) && (((sg >> 5) & 7) != wg) && !(donemask & (1u << i));
          if (act) {
            if ((unsigned)(v[i] >> 32) == T) {
              int b = sg >> 8, P = sg & 255;
              int sl = (P >> 2) ^ (b & 7);
              *(unsigned*)(&h_lds[p1][b][sl * 8 + ((P & 3) << 1)]) = (unsigned)v[i];
              donemask |= 1u << i;
            } else {
              alldone = false;
            }
          }
        }
      } while (!alldone);
    }
    __syncthreads();

    xr_c = xr_n; xz_c = xz_n; xn_c = xn_n; mx_c = mx_n;
  }
}

extern "C" void kernel_launch(void* const* d_in, const int* in_sizes, int n_in,
                              void* d_out, int out_size, void* d_ws, size_t ws_size,
                              hipStream_t stream) {
  (void)in_sizes; (void)n_in; (void)out_size; (void)ws_size;
  const float* x    = (const float*)d_in[0];
  const float* Wp   = (const float*)d_in[1];
  const float* bp   = (const float*)d_in[2];
  const float* ln_g = (const float*)d_in[3];
  const float* ln_b = (const float*)d_in[4];
  const float* cw0  = (const float*)d_in[5];
  const float* cb0  = (const float*)d_in[6];
  const float* cw1  = (const float*)d_in[7];
  const float* cb1  = (const float*)d_in[8];
  const float* cw2  = (const float*)d_in[9];
  const float* cb2  = (const float*)d_in[10];
  const float* bng  = (const float*)d_in[11];
  const float* bnb  = (const float*)d_in[12];
  const float* gW   = (const float*)d_in[13];
  const float* gb   = (const float*)d_in[14];
  const float* Wih  = (const float*)d_in[15];
  const float* Whh  = (const float*)d_in[16];
  const float* bih  = (const float*)d_in[17];
  const float* bhh  = (const float*)d_in[18];

  char* ws = (char*)d_ws;
  u16*   xg    = (u16*)(ws + 0);
  float* ln    = (float*)(ws + 0);  // alias: consumed (by k_mix) before k_gemm writes xg
  u16*   mixbf = (u16*)(ws + (size_t)96 * 1024 * 1024);
  u16*   wihbf = (u16*)(ws + (size_t)128 * 1024 * 1024);
  u64*   hst   = (u64*)(ws + (size_t)134 * 1024 * 1024);
  float* hbuf  = (float*)d_out;     // inter-layer h lives in d_out

  k_init<<<dim3(32), dim3(256), 0, stream>>>(hst, 2 * 4096);
  k_cvt<<<dim3(3072), dim3(256), 0, stream>>>(Wih, wihbf, NL_ * H3_ * H_);
  k_proj<<<dim3(B_ * L_ / 8), dim3(512), 0, stream>>>(x, Wp, bp, hbuf);

  for (int l = 0; l < NL_; ++l) {
    k_ln<<<dim3(B_ * L_ / 4), dim3(256), 0, stream>>>(hbuf, ln_g + l * H_, ln_b + l * H_, ln);
    k_mix<<<dim3(B_ * L_), dim3(512), 0, stream>>>(ln,
        cw0 + l * H_ * 5,  cb0 + l * H_,
        cw1 + l * H_ * 11, cb1 + l * H_,
        cw2 + l * H_ * 23, cb2 + l * H_,
        bng + l * 3 * H_, bnb + l * 3 * H_,
        gW + l * 3 * H3_, gb + l * 3, mixbf);
    k_gemm<<<dim3((B_ * L_ / 128) * (H3_ / 128)), dim3(256), 0, stream>>>(
        mixbf, wihbf + (size_t)l * H3_ * H_, bih + l * H3_, xg);

    const float* whh_l = Whh + (size_t)l * H3_ * H_;
    const float* bhh_l = bhh + l * H3_;
    const u16* xg_c = xg;
    const u16* mix_c = mixbf;
    float* outp = hbuf;
    int tbase = l * L_;
    void* args[] = { (void*)&whh_l, (void*)&bhh_l, (void*)&xg_c, (void*)&mix_c,
                     (void*)&outp, (void*)&hst, (void*)&tbase };
    hipLaunchCooperativeKernel((void*)k_gru, dim3(8), dim3(384), args, 0, stream);
  }
}

// Round 6
// 18947.398 us; speedup vs baseline: 1.5961x; 1.5961x over previous
//
#include <hip/hip_runtime.h>
#include <hip/hip_bf16.h>

// xLSTMStack: proj -> 4x( LN -> conv-mix -> bf16 MFMA GEMM (xg) -> cooperative GRU scan + residual )
// GRU v6: round-2 per-batch rings (256 WGs = (b,s), 512 thr) + weights packed
// bf16 in LDS (96KB/WG) + per-step weight-register prefetch issued early so the
// LDS stream hides under the publish->poll L3 window. h fp32 in LDS, skewed
// (36 floats/slice) to break bank conflicts. Tagged u64 (tag32|f32) slots,
// one poll slot per thread, one __syncthreads per step.
// Workspace (~134.4 MiB):
//   [0,96M)    xg bf16 [B*L*3H] (first 64 MiB aliased as ln fp32)
//   [96,128M)  mixbf bf16 [B*L*H]
//   [128,134M) wihbf bf16 [4*3H*H]
//   [134M,+128K) hst u64 [2][16][512]
// d_out (fp32 [B,L,H]) doubles as the inter-layer h buffer.

#define B_   16
#define L_   2048
#define IN_  64
#define H_   512
#define H3_  1536
#define NL_  4

typedef unsigned short u16;
typedef unsigned long long u64;
typedef short bf16x8 __attribute__((ext_vector_type(8)));
typedef float f32x4 __attribute__((ext_vector_type(4)));

__device__ __forceinline__ u16 f2bf(float f) {
  unsigned u = __float_as_uint(f);
  u = u + 0x7fffu + ((u >> 16) & 1u);
  return (u16)(u >> 16);
}
__device__ __forceinline__ float bf2f(u16 v) {
  return __uint_as_float(((unsigned)v) << 16);
}
__device__ __forceinline__ float gelu_exact(float x) {
  return 0.5f * x * (1.f + erff(x * 0.70710678118654752440f));
}
__device__ __forceinline__ float fast_sig(float x) {
  float e = __expf(-x);
  return __builtin_amdgcn_rcpf(1.f + e);
}
__device__ __forceinline__ float fast_tanh(float x) {
  x = fminf(fmaxf(x, -15.f), 15.f);
  float e = __expf(2.f * x);
  return (e - 1.f) * __builtin_amdgcn_rcpf(e + 1.f);
}
// 8 bf16 (packed in uint4, k-ascending) dot 8 fp32
__device__ __forceinline__ float dotw(uint4 wp, float4 ha, float4 hc) {
  float acc;
  acc  = __uint_as_float(wp.x << 16)          * ha.x;
  acc += __uint_as_float(wp.x & 0xffff0000u)  * ha.y;
  acc += __uint_as_float(wp.y << 16)          * ha.z;
  acc += __uint_as_float(wp.y & 0xffff0000u)  * ha.w;
  acc += __uint_as_float(wp.z << 16)          * hc.x;
  acc += __uint_as_float(wp.z & 0xffff0000u)  * hc.y;
  acc += __uint_as_float(wp.w << 16)          * hc.z;
  acc += __uint_as_float(wp.w & 0xffff0000u)  * hc.w;
  return acc;
}

// ---------------- init: zero tagged h-state ----------------
__global__ void k_init(u64* hst, int n) {
  int i = blockIdx.x * blockDim.x + threadIdx.x;
  if (i < n) hst[i] = 0ull;
}

// ---------------- fp32 -> bf16 convert ----------------
__global__ void k_cvt(const float* __restrict__ in, u16* __restrict__ out, int n) {
  int i = blockIdx.x * blockDim.x + threadIdx.x;
  int stride = gridDim.x * blockDim.x;
  for (; i < n; i += stride) out[i] = f2bf(in[i]);
}

// ---------------- input projection: h = x @ Wp.T + bp ----------------
__global__ __launch_bounds__(512)
void k_proj(const float* __restrict__ x, const float* __restrict__ Wp,
            const float* __restrict__ bp, float* __restrict__ hb) {
  __shared__ float4 xs[128];
  const int tid = threadIdx.x;
  const size_t m0 = (size_t)blockIdx.x * 8;
  if (tid < 128) xs[tid] = ((const float4*)(x + m0 * IN_))[tid];
  __syncthreads();
  float4 wv[16];
  const float4* wp4 = (const float4*)(Wp + (size_t)tid * IN_);
#pragma unroll
  for (int i = 0; i < 16; ++i) wv[i] = wp4[i];
  float acc[8] = {0.f,0.f,0.f,0.f,0.f,0.f,0.f,0.f};
#pragma unroll
  for (int k = 0; k < 16; ++k) {
    float4 w4 = wv[k];
#pragma unroll
    for (int rr = 0; rr < 8; ++rr) {
      float4 xv = xs[rr * 16 + k];
      acc[rr] += w4.x * xv.x + w4.y * xv.y + w4.z * xv.z + w4.w * xv.w;
    }
  }
  float bpv = bp[tid];
#pragma unroll
  for (int rr = 0; rr < 8; ++rr) hb[(m0 + rr) * H_ + tid] = acc[rr] + bpv;
}

// ---------------- LayerNorm (one wave per row) ----------------
__global__ __launch_bounds__(256)
void k_ln(const float* __restrict__ hin, const float* __restrict__ g,
          const float* __restrict__ bta, float* __restrict__ lnout) {
  const int w = threadIdx.x >> 6, lane = threadIdx.x & 63;
  const size_t m = (size_t)blockIdx.x * 4 + w;
  const float4* src = (const float4*)(hin + m * H_);
  float4 a = src[lane * 2], c = src[lane * 2 + 1];
  float sm = a.x + a.y + a.z + a.w + c.x + c.y + c.z + c.w;
  float sq = a.x*a.x + a.y*a.y + a.z*a.z + a.w*a.w + c.x*c.x + c.y*c.y + c.z*c.z + c.w*c.w;
  sm += __shfl_xor(sm, 1);  sq += __shfl_xor(sq, 1);
  sm += __shfl_xor(sm, 2);  sq += __shfl_xor(sq, 2);
  sm += __shfl_xor(sm, 4);  sq += __shfl_xor(sq, 4);
  sm += __shfl_xor(sm, 8);  sq += __shfl_xor(sq, 8);
  sm += __shfl_xor(sm, 16); sq += __shfl_xor(sq, 16);
  sm += __shfl_xor(sm, 32); sq += __shfl_xor(sq, 32);
  float mu = sm * (1.f / 512.f);
  float var = sq * (1.f / 512.f) - mu * mu;
  float inv = 1.f / sqrtf(var + 1e-5f);
  const float4* g4 = (const float4*)g;
  const float4* b4 = (const float4*)bta;
  float4 ga = g4[lane * 2], gc = g4[lane * 2 + 1];
  float4 ba = b4[lane * 2], bc = b4[lane * 2 + 1];
  float4 oa, oc;
  oa.x = (a.x - mu) * inv * ga.x + ba.x;
  oa.y = (a.y - mu) * inv * ga.y + ba.y;
  oa.z = (a.z - mu) * inv * ga.z + ba.z;
  oa.w = (a.w - mu) * inv * ga.w + ba.w;
  oc.x = (c.x - mu) * inv * gc.x + bc.x;
  oc.y = (c.y - mu) * inv * gc.y + bc.y;
  oc.z = (c.z - mu) * inv * gc.z + bc.z;
  oc.w = (c.w - mu) * inv * gc.w + bc.w;
  float4* dst = (float4*)(lnout + m * H_);
  dst[lane * 2] = oa;
  dst[lane * 2 + 1] = oc;
}

// ---------------- fused conv(5,11,23)+BN+GELU+gate softmax+mix ----------------
__global__ __launch_bounds__(512)
void k_mix(const float* __restrict__ ln,
           const float* __restrict__ w0, const float* __restrict__ cb0,
           const float* __restrict__ w1, const float* __restrict__ cb1,
           const float* __restrict__ w2, const float* __restrict__ cb2,
           const float* __restrict__ bng, const float* __restrict__ bnb,
           const float* __restrict__ gW, const float* __restrict__ gb,
           u16* __restrict__ mixbf) {
  const int h = threadIdx.x;
  const int bi = blockIdx.x >> 11;
  const int t = blockIdx.x & (L_ - 1);
  const size_t mrow = (size_t)blockIdx.x;
  float v[23];
#pragma unroll
  for (int d = 0; d < 23; ++d) {
    int tt = t + d - 11;
    v[d] = (tt >= 0 && tt < L_) ? ln[((size_t)bi * L_ + tt) * H_ + h] : 0.f;
  }
  float o0 = cb0[h], o1 = cb1[h], o2 = cb2[h];
#pragma unroll
  for (int d = 0; d < 5; ++d) o0 += v[9 + d] * w0[h * 5 + d];
#pragma unroll
  for (int d = 0; d < 11; ++d) o1 += v[6 + d] * w1[h * 11 + d];
#pragma unroll
  for (int d = 0; d < 23; ++d) o2 += v[d] * w2[h * 23 + d];
  const float bscale = 0.99999500003749968f;  // 1/sqrt(1+1e-5)
  o0 = o0 * (bng[0 * H_ + h] * bscale) + bnb[0 * H_ + h];
  o1 = o1 * (bng[1 * H_ + h] * bscale) + bnb[1 * H_ + h];
  o2 = o2 * (bng[2 * H_ + h] * bscale) + bnb[2 * H_ + h];
  o0 = gelu_exact(o0); o1 = gelu_exact(o1); o2 = gelu_exact(o2);
  float l0 = o0 * gW[0 * H3_ + h] + o1 * gW[0 * H3_ + H_ + h] + o2 * gW[0 * H3_ + 2 * H_ + h];
  float l1 = o0 * gW[1 * H3_ + h] + o1 * gW[1 * H3_ + H_ + h] + o2 * gW[1 * H3_ + 2 * H_ + h];
  float l2 = o0 * gW[2 * H3_ + h] + o1 * gW[2 * H3_ + H_ + h] + o2 * gW[2 * H3_ + 2 * H_ + h];
  l0 += __shfl_xor(l0, 1);  l1 += __shfl_xor(l1, 1);  l2 += __shfl_xor(l2, 1);
  l0 += __shfl_xor(l0, 2);  l1 += __shfl_xor(l1, 2);  l2 += __shfl_xor(l2, 2);
  l0 += __shfl_xor(l0, 4);  l1 += __shfl_xor(l1, 4);  l2 += __shfl_xor(l2, 4);
  l0 += __shfl_xor(l0, 8);  l1 += __shfl_xor(l1, 8);  l2 += __shfl_xor(l2, 8);
  l0 += __shfl_xor(l0, 16); l1 += __shfl_xor(l1, 16); l2 += __shfl_xor(l2, 16);
  l0 += __shfl_xor(l0, 32); l1 += __shfl_xor(l1, 32); l2 += __shfl_xor(l2, 32);
  __shared__ float red[8][3];
  const int w = h >> 6, lane = h & 63;
  if (lane == 0) { red[w][0] = l0; red[w][1] = l1; red[w][2] = l2; }
  __syncthreads();
  l0 = gb[0]; l1 = gb[1]; l2 = gb[2];
#pragma unroll
  for (int i = 0; i < 8; ++i) { l0 += red[i][0]; l1 += red[i][1]; l2 += red[i][2]; }
  float mx = fmaxf(l0, fmaxf(l1, l2));
  float e0 = expf(l0 - mx), e1 = expf(l1 - mx), e2 = expf(l2 - mx);
  float inv = 1.f / (e0 + e1 + e2);
  float out = (o0 * e0 + o1 * e1 + o2 * e2) * inv;
  mixbf[mrow * H_ + h] = f2bf(out);
}

// ---------------- bf16 MFMA GEMM: xg = mixbf @ WihT + bih ----------------
__global__ __launch_bounds__(256)
void k_gemm(const u16* __restrict__ A, const u16* __restrict__ Bm,
            const float* __restrict__ bias, u16* __restrict__ C) {
  __shared__ u16 As[128 * 32];
  __shared__ u16 Bs[128 * 32];
  const int tid = threadIdx.x;
  const int bm = blockIdx.x / 12, bn = blockIdx.x % 12;
  const int m0 = bm * 128, n0 = bn * 128;
  const int w = tid >> 6, lane = tid & 63;
  const int wr = w >> 1, wc = w & 1;
  const int q = lane >> 4, r = lane & 15;
  f32x4 acc[4][4] = {};
  const uint4* Ag = (const uint4*)(A + (size_t)m0 * H_);
  const uint4* Bg = (const uint4*)(Bm + (size_t)n0 * H_);
  uint4* As4 = (uint4*)As;
  uint4* Bs4 = (uint4*)Bs;
  for (int ko = 0; ko < 16; ++ko) {
    __syncthreads();
#pragma unroll
    for (int i = 0; i < 2; ++i) {
      int j = tid + 256 * i;
      As4[j] = Ag[(size_t)(j >> 2) * 64 + (j & 3) + ko * 4];
      Bs4[j] = Bg[(size_t)(j >> 2) * 64 + (j & 3) + ko * 4];
    }
    __syncthreads();
    bf16x8 av[4], bv[4];
#pragma unroll
    for (int m = 0; m < 4; ++m) av[m] = *(const bf16x8*)&As[(wr * 64 + m * 16 + r) * 32 + q * 8];
#pragma unroll
    for (int n = 0; n < 4; ++n) bv[n] = *(const bf16x8*)&Bs[(wc * 64 + n * 16 + r) * 32 + q * 8];
#pragma unroll
    for (int m = 0; m < 4; ++m)
#pragma unroll
      for (int n = 0; n < 4; ++n)
        acc[m][n] = __builtin_amdgcn_mfma_f32_16x16x32_bf16(av[m], bv[n], acc[m][n], 0, 0, 0);
  }
#pragma unroll
  for (int n = 0; n < 4; ++n) {
    int col = n0 + wc * 64 + n * 16 + r;
    float bv_ = bias[col];
#pragma unroll
    for (int m = 0; m < 4; ++m) {
      int row = m0 + wr * 64 + m * 16 + q * 4;
#pragma unroll
      for (int i = 0; i < 4; ++i) {
        float v = acc[m][n][i] + bv_;
        C[(size_t)(row + i) * H3_ + col] = f2bf(v);
      }
    }
  }
}

// ---------------- cooperative GRU scan v6 ----------------
// 256 WGs x 512 thr, wg = b*16+s (per-batch rings of 16 WGs; batches decoupled).
// WG owns dims [32s,32s+32) = 96 gate rows. Thread (w,g16,l16): dim jj=4w+g16,
// rows {jj,512+jj,1024+jj}, k-slice [32*l16,+32). Weights: packed bf16 in LDS
// w_lds[tid][104] as [chunk c'][row q][8]; per step 12 ds_read_b128 prefetched
// EARLY (next step's regs) so the stream hides under publish->poll.
// h fp32 in LDS, slice-skewed (36 floats/slice). Tag u64 (tag32|f32), 1 slot/thread.
__global__ __launch_bounds__(512, 1)
void k_gru(const float* __restrict__ Whh_l, const float* __restrict__ bhh_l,
           const u16* __restrict__ xg, const u16* __restrict__ mixbf,
           float* __restrict__ out_h, u64* hst, int tbase) {
  const int tid = threadIdx.x;
  const int wg = blockIdx.x;
  const int b = wg >> 4, s = wg & 15;
  const int w = tid >> 6, lane = tid & 63;
  const int g16 = lane >> 4, l16 = lane & 15;
  const int jj = 4 * w + g16;
  const int d_own = s * 32 + jj;
  const bool gl = (l16 == 0);

  __shared__ __align__(16) u16 w_lds[512][104];   // 104 KiB
  __shared__ __align__(16) float h_lds[2][576];   // 4.5 KiB, skewed

  // ---- startup: pack this thread's 3x32 weight slice into LDS (bf16) ----
  {
    const float* s0 = Whh_l + ((size_t)0 * H_ + d_own) * H_ + l16 * 32;
    const float* s1 = Whh_l + ((size_t)1 * H_ + d_own) * H_ + l16 * 32;
    const float* s2 = Whh_l + ((size_t)2 * H_ + d_own) * H_ + l16 * 32;
#pragma unroll
    for (int c = 0; c < 4; ++c) {
      float4 a, v; u16* dst;
      a = *(const float4*)(s0 + c * 8); v = *(const float4*)(s0 + c * 8 + 4);
      dst = &w_lds[tid][c * 24 + 0];
      dst[0]=f2bf(a.x); dst[1]=f2bf(a.y); dst[2]=f2bf(a.z); dst[3]=f2bf(a.w);
      dst[4]=f2bf(v.x); dst[5]=f2bf(v.y); dst[6]=f2bf(v.z); dst[7]=f2bf(v.w);
      a = *(const float4*)(s1 + c * 8); v = *(const float4*)(s1 + c * 8 + 4);
      dst = &w_lds[tid][c * 24 + 8];
      dst[0]=f2bf(a.x); dst[1]=f2bf(a.y); dst[2]=f2bf(a.z); dst[3]=f2bf(a.w);
      dst[4]=f2bf(v.x); dst[5]=f2bf(v.y); dst[6]=f2bf(v.z); dst[7]=f2bf(v.w);
      a = *(const float4*)(s2 + c * 8); v = *(const float4*)(s2 + c * 8 + 4);
      dst = &w_lds[tid][c * 24 + 16];
      dst[0]=f2bf(a.x); dst[1]=f2bf(a.y); dst[2]=f2bf(a.z); dst[3]=f2bf(a.w);
      dst[4]=f2bf(v.x); dst[5]=f2bf(v.y); dst[6]=f2bf(v.z); dst[7]=f2bf(v.w);
    }
  }
  const float br_ = bhh_l[0 * H_ + d_own];
  const float bz_ = bhh_l[1 * H_ + d_own];
  const float bn_ = bhh_l[2 * H_ + d_own];

  // h_{-1} = 0 (skewed slot for dim tid)
  h_lds[0][(tid >> 5) * 36 + (tid & 31)] = 0.f;
  float hp = 0.f;
  __syncthreads();

  const u16* xgp = xg + (size_t)b * L_ * H3_ + d_own;
  const u16* mxp = mixbf + (size_t)b * L_ * H_ + d_own;
  float* outp = out_h + (size_t)b * L_ * H_ + d_own;
  const char* wbase = (const char*)&w_lds[tid][0];

  // prologue: weight regs + t=0 gate inputs
  uint4 wv[4][3];
#pragma unroll
  for (int c = 0; c < 4; ++c) {
    const int cp = (c + g16) & 3;
    wv[c][0] = *(const uint4*)(wbase + cp * 48);
    wv[c][1] = *(const uint4*)(wbase + cp * 48 + 16);
    wv[c][2] = *(const uint4*)(wbase + cp * 48 + 32);
  }
  u16 xr_c = 0, xz_c = 0, xn_c = 0, mx_c = 0;
  if (gl) {
    xr_c = xgp[0]; xz_c = xgp[H_]; xn_c = xgp[2 * H_]; mx_c = mxp[0];
  }

  for (int t = 0; t < L_; ++t) {
    const int cur = t & 1, nxt = cur ^ 1;
    const unsigned T = (unsigned)(tbase + t + 1);

    // prefetch next step's gate inputs (HBM latency hides under this step)
    u16 xr_n = 0, xz_n = 0, xn_n = 0, mx_n = 0;
    if (gl && t + 1 < L_) {
      const u16* xq = xgp + (size_t)(t + 1) * H3_;
      xr_n = xq[0]; xz_n = xq[H_]; xn_n = xq[2 * H_];
      mx_n = mxp[(size_t)(t + 1) * H_];
    }

    // ---- matvec: 3 rows x 32 k, weights in regs, h from skewed LDS ----
    const float* hb = &h_lds[cur][l16 * 36];
    float q0 = 0.f, q1 = 0.f, q2 = 0.f;
#pragma unroll
    for (int c = 0; c < 4; ++c) {
      const int cp = (c + g16) & 3;
      float4 ha = *(const float4*)(hb + cp * 8);
      float4 hc = *(const float4*)(hb + cp * 8 + 4);
      q0 += dotw(wv[c][0], ha, hc);
      q1 += dotw(wv[c][1], ha, hc);
      q2 += dotw(wv[c][2], ha, hc);
    }

    // prefetch next step's weight regs NOW (completes during publish/poll;
    // __syncthreads at loop end keeps them ordered before next matvec)
#pragma unroll
    for (int c = 0; c < 4; ++c) {
      const int cp = (c + g16) & 3;
      wv[c][0] = *(const uint4*)(wbase + cp * 48);
      wv[c][1] = *(const uint4*)(wbase + cp * 48 + 16);
      wv[c][2] = *(const uint4*)(wbase + cp * 48 + 32);
    }

    // reduce over 16 k-slices
    q0 += __shfl_xor(q0, 1); q1 += __shfl_xor(q1, 1); q2 += __shfl_xor(q2, 1);
    q0 += __shfl_xor(q0, 2); q1 += __shfl_xor(q1, 2); q2 += __shfl_xor(q2, 2);
    q0 += __shfl_xor(q0, 4); q1 += __shfl_xor(q1, 4); q2 += __shfl_xor(q2, 4);
    q0 += __shfl_xor(q0, 8); q1 += __shfl_xor(q1, 8); q2 += __shfl_xor(q2, 8);

    if (gl) {
      float r = fast_sig(bf2f(xr_c) + q0 + br_);
      float z = fast_sig(bf2f(xz_c) + q1 + bz_);
      float n = fast_tanh(bf2f(xn_c) + r * (q2 + bn_));
      float hnew = n + z * (hp - n);
      hp = hnew;
      if (t + 1 < L_) {  // publish first: it's on the other WGs' critical path
        __hip_atomic_store(&hst[(size_t)nxt * 8192 + (b << 9) + d_own],
                           ((u64)T << 32) | (u64)__float_as_uint(hnew),
                           __ATOMIC_RELAXED, __HIP_MEMORY_SCOPE_AGENT);
        h_lds[nxt][s * 36 + jj] = hnew;   // own dim straight to LDS
      }
      outp[(size_t)t * H_] = bf2f(mx_c) + hnew;
    }

    // ---- poll: thread tid owns dim tid of own batch ----
    if (t + 1 < L_ && (tid >> 5) != s) {
      u64* sl = &hst[(size_t)nxt * 8192 + (b << 9) + tid];
      u64 v;
      do {
        v = __hip_atomic_load(sl, __ATOMIC_RELAXED, __HIP_MEMORY_SCOPE_AGENT);
      } while ((unsigned)(v >> 32) != T);
      h_lds[nxt][(tid >> 5) * 36 + (tid & 31)] = __uint_as_float((unsigned)v);
    }
    __syncthreads();

    xr_c = xr_n; xz_c = xz_n; xn_c = xn_n; mx_c = mx_n;
  }
}

extern "C" void kernel_launch(void* const* d_in, const int* in_sizes, int n_in,
                              void* d_out, int out_size, void* d_ws, size_t ws_size,
                              hipStream_t stream) {
  (void)in_sizes; (void)n_in; (void)out_size; (void)ws_size;
  const float* x    = (const float*)d_in[0];
  const float* Wp   = (const float*)d_in[1];
  const float* bp   = (const float*)d_in[2];
  const float* ln_g = (const float*)d_in[3];
  const float* ln_b = (const float*)d_in[4];
  const float* cw0  = (const float*)d_in[5];
  const float* cb0  = (const float*)d_in[6];
  const float* cw1  = (const float*)d_in[7];
  const float* cb1  = (const float*)d_in[8];
  const float* cw2  = (const float*)d_in[9];
  const float* cb2  = (const float*)d_in[10];
  const float* bng  = (const float*)d_in[11];
  const float* bnb  = (const float*)d_in[12];
  const float* gW   = (const float*)d_in[13];
  const float* gb   = (const float*)d_in[14];
  const float* Wih  = (const float*)d_in[15];
  const float* Whh  = (const float*)d_in[16];
  const float* bih  = (const float*)d_in[17];
  const float* bhh  = (const float*)d_in[18];

  char* ws = (char*)d_ws;
  u16*   xg    = (u16*)(ws + 0);
  float* ln    = (float*)(ws + 0);  // alias: consumed (by k_mix) before k_gemm writes xg
  u16*   mixbf = (u16*)(ws + (size_t)96 * 1024 * 1024);
  u16*   wihbf = (u16*)(ws + (size_t)128 * 1024 * 1024);
  u64*   hst   = (u64*)(ws + (size_t)134 * 1024 * 1024);
  float* hbuf  = (float*)d_out;     // inter-layer h lives in d_out

  k_init<<<dim3(64), dim3(256), 0, stream>>>(hst, 2 * B_ * H_);
  k_cvt<<<dim3(3072), dim3(256), 0, stream>>>(Wih, wihbf, NL_ * H3_ * H_);
  k_proj<<<dim3(B_ * L_ / 8), dim3(512), 0, stream>>>(x, Wp, bp, hbuf);

  for (int l = 0; l < NL_; ++l) {
    k_ln<<<dim3(B_ * L_ / 4), dim3(256), 0, stream>>>(hbuf, ln_g + l * H_, ln_b + l * H_, ln);
    k_mix<<<dim3(B_ * L_), dim3(512), 0, stream>>>(ln,
        cw0 + l * H_ * 5,  cb0 + l * H_,
        cw1 + l * H_ * 11, cb1 + l * H_,
        cw2 + l * H_ * 23, cb2 + l * H_,
        bng + l * 3 * H_, bnb + l * 3 * H_,
        gW + l * 3 * H3_, gb + l * 3, mixbf);
    k_gemm<<<dim3((B_ * L_ / 128) * (H3_ / 128)), dim3(256), 0, stream>>>(
        mixbf, wihbf + (size_t)l * H3_ * H_, bih + l * H3_, xg);

    const float* whh_l = Whh + (size_t)l * H3_ * H_;
    const float* bhh_l = bhh + l * H3_;
    const u16* xg_c = xg;
    const u16* mix_c = mixbf;
    float* outp = hbuf;
    int tbase = l * L_;
    void* args[] = { (void*)&whh_l, (void*)&bhh_l, (void*)&xg_c, (void*)&mix_c,
                     (void*)&outp, (void*)&hst, (void*)&tbase };
    hipLaunchCooperativeKernel((void*)k_gru, dim3(B_ * 16), dim3(512), args, 0, stream);
  }
}